// Round 7
// baseline (509.515 us; speedup 1.0000x reference)
//
#include <hip/hip_runtime.h>

#define N 8192
#define D 128

typedef __attribute__((ext_vector_type(8))) short short8;   // 8 bf16 = 4 VGPRs
typedef __attribute__((ext_vector_type(4))) float float4v;  // MFMA C/D

__device__ __forceinline__ unsigned short f32_to_bf16(float f) {
    unsigned int u = __float_as_uint(f);
    unsigned int r = (u + 0x7fffu + ((u >> 16) & 1u)) >> 16;
    return (unsigned short)r;
}

__device__ __forceinline__ float wave_reduce(float p) {
    #pragma unroll
    for (int off = 32; off > 0; off >>= 1)
        p += __shfl_xor(p, off, 64);
    return p;
}

// ---------------- Prologue: ybf = bf16(W + b); reg partials = 0.05*||Y||^2 ----
__global__ __launch_bounds__(256)
void gf_prep_kernel(const float* __restrict__ W, const float* __restrict__ b,
                    unsigned short* __restrict__ ybf, float* __restrict__ regp) {
    __shared__ float s_ws[4];
    const int t = blockIdx.x * 256 + threadIdx.x;
    const int f = t * 4;
    const int dcol = f & (D - 1);
    const float4 wv = *(const float4*)(W + f);
    const float4 bv = *(const float4*)(b + dcol);
    const float y0 = wv.x + bv.x, y1 = wv.y + bv.y, y2 = wv.z + bv.z, y3 = wv.w + bv.w;

    ushort4 o;
    o.x = f32_to_bf16(y0); o.y = f32_to_bf16(y1);
    o.z = f32_to_bf16(y2); o.w = f32_to_bf16(y3);
    *(ushort4*)(ybf + f) = o;

    float s = y0*y0 + y1*y1 + y2*y2 + y3*y3;
    s = wave_reduce(s);
    const int lane = threadIdx.x & 63, w = threadIdx.x >> 6;
    if (lane == 0) s_ws[w] = s;
    __syncthreads();
    if (threadIdx.x == 0)
        regp[blockIdx.x] = 0.05f * (s_ws[0] + s_ws[1] + s_ws[2] + s_ws[3]);
}

// ---------------- Phase A: dense C = bf16(Y Y^T), row-major ----------------
// Same verified MFMA + wave-private LDS roundtrip as R6, but instead of
// comparing with A it STORES the 128x128 C tile (bf16, row-major, coalesced).
// No A reads here; the only global traffic is L2-resident ybf + C writes.
__global__ __launch_bounds__(256, 4)
void gf_gemm_kernel(const unsigned short* __restrict__ ybf,
                    unsigned short* __restrict__ C) {
    __shared__ float s_c[4][16][132];   // wave-private stripes

    const int lane = threadIdx.x & 63;
    const int w    = threadIdx.x >> 6;
    const int j0   = blockIdx.x * 128;              // fastest dim = columns
    const int i0   = blockIdx.y * 128 + w * 32;
    const int r16  = lane & 15;
    const int quad = lane >> 4;
    const int l32  = lane & 31;
    const int half = lane >> 5;

    short8 afr[2][4];
    #pragma unroll
    for (int s = 0; s < 2; ++s) {
        const unsigned short* yrow = ybf + (size_t)(i0 + s * 16 + r16) * D;
        #pragma unroll
        for (int c = 0; c < 4; ++c)
            afr[s][c] = *(const short8*)(yrow + c * 32 + quad * 8);
    }

    #pragma unroll
    for (int s = 0; s < 2; ++s) {
        #pragma unroll
        for (int jj = 0; jj < 8; ++jj) {
            const int jbase = j0 + jj * 16;
            short8 bfr[4];
            const unsigned short* yrow = ybf + (size_t)(jbase + r16) * D;
            #pragma unroll
            for (int c = 0; c < 4; ++c)
                bfr[c] = *(const short8*)(yrow + c * 32 + quad * 8);
            float4v acc = {0.f, 0.f, 0.f, 0.f};
            #pragma unroll
            for (int c = 0; c < 4; ++c)
                acc = __builtin_amdgcn_mfma_f32_16x16x32_bf16(afr[s][c], bfr[c], acc, 0, 0, 0);
            #pragma unroll
            for (int r = 0; r < 4; ++r)
                s_c[w][quad * 4 + r][jj * 16 + r16] = acc[r];
        }
        // row-major readback + coalesced bf16x4 store
        #pragma unroll
        for (int t = 0; t < 8; ++t) {
            const int m = 2 * t + half;
            const float4 cv = *(const float4*)&s_c[w][m][l32 * 4];
            ushort4 o;
            o.x = f32_to_bf16(cv.x); o.y = f32_to_bf16(cv.y);
            o.z = f32_to_bf16(cv.z); o.w = f32_to_bf16(cv.w);
            *(ushort4*)(C + (size_t)(i0 + s * 16 + m) * N + j0 + l32 * 4) = o;
        }
    }
}

// ---------------- Phase B: pure two-stream masked loss ---------------------
// Linear grid-stride sweep: float4 of A + ushort4 of C per iteration — the
// m13/fillBuffer access pattern, no fragment reads, no LDS in the hot loop.
// This is the isolation probe for the 1.6 TB/s mystery.
__global__ __launch_bounds__(256)
void gf_loss_kernel(const float4* __restrict__ A4,
                    const ushort4* __restrict__ C4,
                    float* __restrict__ partials) {
    __shared__ float s_ws[4];
    const int tid    = blockIdx.x * 256 + threadIdx.x;
    const int stride = gridDim.x * 256;

    float acc = 0.0f;
    #pragma unroll 2
    for (int idx = tid; idx < N * N / 4; idx += stride) {
        const float4  a = A4[idx];
        const ushort4 c = C4[idx];
        const float c0 = __uint_as_float((unsigned)c.x << 16);
        const float c1 = __uint_as_float((unsigned)c.y << 16);
        const float c2 = __uint_as_float((unsigned)c.z << 16);
        const float c3 = __uint_as_float((unsigned)c.w << 16);
        float d;
        d = a.x - c0; acc += (a.x > 0.0f) ? d * d : 0.0f;
        d = a.y - c1; acc += (a.y > 0.0f) ? d * d : 0.0f;
        d = a.z - c2; acc += (a.z > 0.0f) ? d * d : 0.0f;
        d = a.w - c3; acc += (a.w > 0.0f) ? d * d : 0.0f;
    }

    acc = wave_reduce(acc);
    const int lane = threadIdx.x & 63, w = threadIdx.x >> 6;
    if (lane == 0) s_ws[w] = acc;
    __syncthreads();
    if (threadIdx.x == 0)
        partials[blockIdx.x] = 0.5f * (s_ws[0] + s_ws[1] + s_ws[2] + s_ws[3]);
}

// ---------------- Final reduce: 2048 loss partials + 1024 reg partials -----
__global__ __launch_bounds__(256)
void gf_reduce_kernel(const float* __restrict__ parts, float* __restrict__ out) {
    __shared__ float s_ws[4];
    const int lane = threadIdx.x & 63, w = threadIdx.x >> 6;
    float s = 0.0f;
    for (int i = threadIdx.x; i < 2048 + 1024; i += 256) s += parts[i];
    s = wave_reduce(s);
    if (lane == 0) s_ws[w] = s;
    __syncthreads();
    if (threadIdx.x == 0) out[0] = s_ws[0] + s_ws[1] + s_ws[2] + s_ws[3];
}

extern "C" void kernel_launch(void* const* d_in, const int* in_sizes, int n_in,
                              void* d_out, int out_size, void* d_ws, size_t ws_size,
                              hipStream_t stream) {
    const float* A = (const float*)d_in[0];
    const float* W = (const float*)d_in[1];
    const float* b = (const float*)d_in[2];
    float* out = (float*)d_out;

    char* ws = (char*)d_ws;
    float* parts          = (float*)ws;                      // [0,2048) loss, [2048,3072) reg
    unsigned short* ybf   = (unsigned short*)(ws + 32768);   // 2 MB bf16 Y
    unsigned short* Cbuf  = (unsigned short*)(ws + 32768 + 2097152);  // 134 MB bf16 C

    gf_prep_kernel<<<dim3(N * D / 1024), dim3(256), 0, stream>>>(W, b, ybf, parts + 2048);
    gf_gemm_kernel<<<dim3(64, 64), dim3(256), 0, stream>>>(ybf, Cbuf);
    gf_loss_kernel<<<dim3(2048), dim3(256), 0, stream>>>((const float4*)A,
                                                         (const ushort4*)Cbuf, parts);
    gf_reduce_kernel<<<dim3(1), dim3(256), 0, stream>>>(parts, out);
}